// Round 4
// baseline (793.163 us; speedup 1.0000x reference)
//
#include <hip/hip_runtime.h>
#include <hip/hip_bf16.h>
#include <stdint.h>

// Problem constants (B=2, S=2048, D=1024, E=8, F=2048, K=2)
// Inputs/outputs are FLOAT32 (per reference). Internal compute: bf16 MFMA.
#define D_MODEL 1024
#define NEXP 8
#define FF 2048
#define TOPK 2
#define NTOK 4096                       // B*S tokens
#define MT2 256                         // gemm1 M-tile (rows)
#define MT 128                          // gemm2 M-tile (rows)
#define MAXROWS 10240                   // 8192 + 8*256 (worst-case padded rows)
#define NT256 40                        // 256-row tiles (gemm1)
#define NT128 80                        // 128-row tiles (gemm2)

typedef __bf16 bf16x8 __attribute__((ext_vector_type(8)));
typedef float f32x4 __attribute__((ext_vector_type(4)));

__device__ inline unsigned short f2b(float f){
  __hip_bfloat16 h = __float2bfloat16(f);
  return __builtin_bit_cast(unsigned short, h);
}

// async global->LDS, 16B per lane; LDS dst is wave-uniform base + lane*16
__device__ inline void gl2lds16(const unsigned short* g, unsigned short* l){
  __builtin_amdgcn_global_load_lds(
      (const __attribute__((address_space(1))) unsigned int*)g,
      (__attribute__((address_space(3))) unsigned int*)l, 16, 0, 0);
}

// ---------------- fallback: zero output (diagnostic path if ws too small) ----
__global__ void zero_out_kernel(float* out, int n){
  int i = blockIdx.x*256 + threadIdx.x;
  if (i < n) out[i] = 0.f;
}

// ---------------- fp32 -> bf16 conversion (vectorized) ----------------
__global__ __launch_bounds__(256) void conv_kernel(
    const float* __restrict__ in, unsigned short* __restrict__ out, long n4)
{
  long i = (long)blockIdx.x*256 + threadIdx.x;
  if (i >= n4) return;
  float4 v = reinterpret_cast<const float4*>(in)[i];
  ushort4 o;
  o.x = f2b(v.x); o.y = f2b(v.y); o.z = f2b(v.z); o.w = f2b(v.w);
  reinterpret_cast<ushort4*>(out)[i] = o;
}

// ---------------- bookkeeping kernels ----------------

__global__ void init_kernel(int* perm, int* ctrl){
  int i = blockIdx.x*256 + threadIdx.x;
  if (i < MAXROWS) perm[i] = -1;
  if (i < 64) ctrl[i] = 0;
}

// One wave per token: float4-vectorized logits + fused x->bf16 writeout.
__global__ __launch_bounds__(256) void router_kernel(
    const float* __restrict__ x, const float* __restrict__ rw,
    float* __restrict__ topw, int* __restrict__ tope, int* __restrict__ counts,
    unsigned short* __restrict__ xb)
{
  const int wid = threadIdx.x >> 6, lane = threadIdx.x & 63;
  const int t = blockIdx.x*4 + wid;
  float p[NEXP];
  #pragma unroll
  for (int e=0;e<NEXP;e++) p[e] = 0.f;
  #pragma unroll
  for (int j=0;j<4;j++){
    const int d4 = j*64 + lane;
    float4 xv = reinterpret_cast<const float4*>(x + (long)t*D_MODEL)[d4];
    ushort4 o; o.x=f2b(xv.x); o.y=f2b(xv.y); o.z=f2b(xv.z); o.w=f2b(xv.w);
    reinterpret_cast<ushort4*>(xb + (long)t*D_MODEL)[d4] = o;
    #pragma unroll
    for (int e=0;e<NEXP;e++){
      float4 rv = reinterpret_cast<const float4*>(rw + e*D_MODEL)[d4];
      p[e] += xv.x*rv.x + xv.y*rv.y + xv.z*rv.z + xv.w*rv.w;
    }
  }
  #pragma unroll
  for (int e=0;e<NEXP;e++)
    for (int off=32; off; off>>=1) p[e] += __shfl_xor(p[e], off, 64);
  if (lane == 0){
    float mx = p[0];
    #pragma unroll
    for (int e=1;e<NEXP;e++) mx = fmaxf(mx, p[e]);
    float w[NEXP]; float s = 0.f;
    #pragma unroll
    for (int e=0;e<NEXP;e++){ w[e] = expf(p[e]-mx); s += w[e]; }
    #pragma unroll
    for (int e=0;e<NEXP;e++) w[e] /= s;
    int e1 = 0;
    #pragma unroll
    for (int e=1;e<NEXP;e++) if (w[e] > w[e1]) e1 = e;   // ties -> lowest idx
    int e2 = -1;
    #pragma unroll
    for (int e=0;e<NEXP;e++) if (e != e1 && (e2 < 0 || w[e] > w[e2])) e2 = e;
    float s2 = w[e1] + w[e2];
    topw[t*2+0] = w[e1]/s2;
    topw[t*2+1] = w[e2]/s2;
    tope[t*2+0] = e1; tope[t*2+1] = e2;
    atomicAdd(&counts[e1], 1); atomicAdd(&counts[e2], 1);
  }
}

// pad each expert segment to 256 rows; emit tile->expert for 256- and 128-tiles
__global__ void partition_kernel(const int* ctrl, int* segStart,
                                 int* te256, int* te128){
  if (threadIdx.x == 0 && blockIdx.x == 0){
    int off = 0, t2 = 0, t1 = 0;
    for (int e=0;e<NEXP;e++){
      segStart[e] = off;
      int padded = ((ctrl[e] + MT2 - 1)/MT2)*MT2;
      off += padded;
      for (int k=0;k<padded/MT2 && t2 < NT256;k++) te256[t2++] = e;
      for (int k=0;k<padded/MT  && t1 < NT128;k++) te128[t1++] = e;
    }
    segStart[NEXP] = off;
    while (t2 < NT256) te256[t2++] = -1;
    while (t1 < NT128) te128[t1++] = -1;
  }
}

__global__ void scatter_kernel(const int* tope, const int* segStart, int* fill,
                               int* perm, int* rowOf){
  int i = blockIdx.x*256 + threadIdx.x;           // (token,k) pair index
  int e = tope[i];
  int pos = segStart[e] + atomicAdd(&fill[e], 1);
  if (pos >= 0 && pos < MAXROWS){ perm[pos] = i >> 1; rowOf[i] = pos; }
}

// w2 (E,F,D) fp32 -> w2t (E,D,F) bf16: transpose + convert fused
__global__ void transpose_w2(const float* __restrict__ w2,
                             unsigned short* __restrict__ w2t){
  __shared__ unsigned short tl[32][33];
  const int e = blockIdx.z;
  const int d0 = blockIdx.x*32, f0 = blockIdx.y*32;
  const int tx = threadIdx.x, ty = threadIdx.y;
  #pragma unroll
  for (int i=0;i<4;i++)
    tl[ty + i*8][tx] = f2b(w2[((long)(e*FF + f0 + ty + i*8))*D_MODEL + d0 + tx]);
  __syncthreads();
  #pragma unroll
  for (int i=0;i<4;i++)
    w2t[((long)e*D_MODEL + d0 + ty + i*8)*FF + f0 + tx] = tl[tx][ty + i*8];
}

// ---------------- GEMM1: Hg = silu(Xg @ w1e^T) * (Xg @ v1e^T) ----------------
// 8-wave deep pipeline (T3+T4+T5):
//   BM=256 BN=128 BK=64, 512 thr, waves 2M x 4N, per-wave 128x32 dual-mat.
//   Each K-tile = 4 phases of 16 MFMA; staging = 4 panels/K-tile
//   (A_kk0, B_kk0, A_kk1, B_kk1; 2 loads/thread each), one panel issued per
//   phase into buf^1, uniform s_waitcnt vmcnt(6) per phase (3 panels in
//   flight, never drains; ledger verified: each wait completes exactly the
//   panel needed that phase). One raw barrier per phase; WAR-safe because a
//   phase's stage target region (buf^1 or disjoint kk) never overlaps what
//   a wave past the same barrier can still be reading.
// __launch_bounds__(512, 1): 128 KiB LDS admits only 1 block/CU anyway;
// round-3's (512,2) capped VGPR at 128 = the accumulator alone -> full
// scratch spill (WRITE_SIZE 546 MB, 16x the output). With cap 256 the
// kernel fits (~210 VGPR) and spill traffic disappears.
// Swizzle: chunk c' = c ^ ((row>>1)&3) on both the pre-swizzled global
// source and the ds_read side (2-way bank aliasing = free).
__global__ __launch_bounds__(512, 1) void gemm1_swiglu(
    const unsigned short* __restrict__ x,
    const unsigned short* __restrict__ w1,
    const unsigned short* __restrict__ v1,
    const int* __restrict__ perm,
    const int* __restrict__ te256,
    unsigned short* __restrict__ Hg)
{
  const int b = blockIdx.x;                    // 0..639
  const int xcd = b & 7, s = b >> 3;           // s: 0..79
  const int mt = xcd*5 + (s % 5);              // 0..39 (5-mt stripe per XCD)
  const int nt = s / 5;                        // 0..15
  int e = te256[mt];
  if (e < 0) return;
  e &= 7;
  __shared__ alignas(16) unsigned short As [2][2][8192];  // [buf][kk][256*32]
  __shared__ alignas(16) unsigned short B1s[2][2][4096];  // [buf][kk][128*32]
  __shared__ alignas(16) unsigned short B2s[2][2][4096];
  const int tid = threadIdx.x;
  const int lane = tid & 63;
  const int wid = tid >> 6;
  const int wm = wid >> 2, wn = wid & 3;       // 2M x 4N waves

  // staging addressing: chunk idx -> row = idx>>2, c = idx&3, sc = c^((r>>1)&3)
  const int ra = tid >> 2, ca = tid & 3;
  const int sca = ca ^ ((ra >> 1) & 3);        // (ra+128)>>1 & 3 == same
  int tok0 = perm[mt*MT2 + ra];        if (tok0 < 0 || tok0 >= NTOK) tok0 = 0;
  int tok1 = perm[mt*MT2 + ra + 128];  if (tok1 < 0 || tok1 >= NTOK) tok1 = 0;
  const long aS0 = (long)tok0*D_MODEL + sca*8;
  const long aS1 = (long)tok1*D_MODEL + sca*8;
  const long bS  = ((long)e*FF + nt*128 + ra)*D_MODEL + sca*8;
  const int dA0 = tid*8, dA1 = (tid+512)*8, dB = tid*8;

  f32x4 zero = {0.f,0.f,0.f,0.f};
  f32x4 acc1[8][2], acc2[8][2];
  #pragma unroll
  for (int i=0;i<8;i++)
    #pragma unroll
    for (int j=0;j<2;j++){ acc1[i][j] = zero; acc2[i][j] = zero; }

  // ds_read addressing (row stride = 32 elems within a [kk] panel)
  const int lq = lane >> 4, ll = lane & 15;
  const int scol = (lq ^ ((ll >> 1) & 3)) * 8;        // swizzled chunk offset
  const int aRow = (wm*128 + ll)*32 + scol;           // + (h*64+i*16)*32
  const int nRow = (wn*32  + ll)*32 + scol;           // + j*16*32

#define VMW(n) asm volatile("s_waitcnt vmcnt(" #n ")" ::: "memory")
#define BAR()  do{ asm volatile("" ::: "memory"); __builtin_amdgcn_s_barrier(); \
                   asm volatile("" ::: "memory"); }while(0)
#define STAGE_A(BUF,KK,KT) do{ const long o_ = (long)(KT)*64 + (KK)*32; \
    gl2lds16(x + aS0 + o_, &As[BUF][KK][0] + dA0);                      \
    gl2lds16(x + aS1 + o_, &As[BUF][KK][0] + dA1); }while(0)
#define STAGE_B(BUF,KK,KT) do{ const long o_ = (long)(KT)*64 + (KK)*32; \
    gl2lds16(w1 + bS + o_, &B1s[BUF][KK][0] + dB);                      \
    gl2lds16(v1 + bS + o_, &B2s[BUF][KK][0] + dB); }while(0)
// phase compute: half H_ (0/1), kk via pointers; LOADB_: refresh b frags
#define PHASE(BUF_,KK_,H_,LOADB_) do{                                   \
    const unsigned short* Ap  = &As [BUF_][KK_][0];                     \
    if (LOADB_){                                                        \
      const unsigned short* Bp1 = &B1s[BUF_][KK_][0];                   \
      const unsigned short* Bp2 = &B2s[BUF_][KK_][0];                   \
      _Pragma("unroll")                                                 \
      for (int j=0;j<2;j++){                                            \
        b1f[j] = *(const bf16x8*)&Bp1[nRow + j*512];                    \
        b2f[j] = *(const bf16x8*)&Bp2[nRow + j*512];                    \
      }                                                                 \
    }                                                                   \
    bf16x8 af[4];                                                       \
    _Pragma("unroll")                                                   \
    for (int i=0;i<4;i++) af[i] = *(const bf16x8*)&Ap[aRow + ((H_)*64 + i*16)*32]; \
    __builtin_amdgcn_s_setprio(1);                                      \
    _Pragma("unroll")                                                   \
    for (int i=0;i<4;i++)                                               \
      _Pragma("unroll")                                                 \
      for (int j=0;j<2;j++){                                            \
        acc1[(H_)*4+i][j] = __builtin_amdgcn_mfma_f32_16x16x32_bf16(af[i], b1f[j], acc1[(H_)*4+i][j], 0,0,0); \
        acc2[(H_)*4+i][j] = __builtin_amdgcn_mfma_f32_16x16x32_bf16(af[i], b2f[j], acc2[(H_)*4+i][j], 0,0,0); \
      }                                                                 \
    __builtin_amdgcn_s_setprio(0);                                      \
  }while(0)

  // prologue: stage K-tile 0 fully (4 panels, 8 loads)
  STAGE_A(0,0,0); STAGE_B(0,0,0); STAGE_A(0,1,0); STAGE_B(0,1,0);

  bf16x8 b1f[2], b2f[2];
  const int NKT = D_MODEL/64;                  // 16
  for (int kt=0; kt<NKT; ++kt){
    const int buf = kt & 1, nb = buf ^ 1;
    const bool pre = (kt+1 < NKT);
    // ph0: kk0 half0 (loads B kk0)
    if (pre){ STAGE_A(nb,0,kt+1); VMW(6); } else { VMW(4); }
    BAR();
    if (buf == 0) PHASE(0,0,0,1); else PHASE(1,0,0,1);
    // ph1: kk0 half1
    if (pre){ STAGE_B(nb,0,kt+1); VMW(6); } else { VMW(4); }
    BAR();
    if (buf == 0) PHASE(0,0,1,0); else PHASE(1,0,1,0);
    // ph2: kk1 half0 (loads B kk1)
    if (pre){ STAGE_A(nb,1,kt+1); VMW(6); } else { VMW(0); }
    BAR();
    if (buf == 0) PHASE(0,1,0,1); else PHASE(1,1,0,1);
    // ph3: kk1 half1
    if (pre){ STAGE_B(nb,1,kt+1); VMW(6); } else { VMW(0); }
    BAR();
    if (buf == 0) PHASE(0,1,1,0); else PHASE(1,1,1,0);
  }
#undef PHASE
#undef STAGE_A
#undef STAGE_B
#undef VMW
#undef BAR

  // epilogue: h = silu(g)*u, write bf16.  C/D: col=lane&15, row=(lane>>4)*4+rr
  const int mrowB = mt*MT2 + wm*128 + lq*4;
  const int ncolB = nt*128 + wn*32 + ll;
  #pragma unroll
  for (int m=0;m<8;m++)
    #pragma unroll
    for (int j=0;j<2;j++)
      #pragma unroll
      for (int rr=0;rr<4;rr++){
        float g = acc1[m][j][rr];
        float u = acc2[m][j][rr];
        float h = (g / (1.0f + __expf(-g))) * u;
        Hg[(long)(mrowB + m*16 + rr)*FF + (ncolB + j*16)] = f2b(h);
      }
}

// ---------------- GEMM2: Yg(fp32) = Hg @ w2e  (B from transposed w2t) --------
// 3-buffer depth-2 ring (verified round 2); 48 KB LDS -> 3 blocks/CU.
__global__ __launch_bounds__(256, 3) void gemm2_kernel(
    const unsigned short* __restrict__ Hg,
    const unsigned short* __restrict__ w2t,   // [E][D][F] bf16
    const int* __restrict__ te128,
    float* __restrict__ Yg)
{
#define KSTEP 32
  const int b = blockIdx.x;                    // 0..639
  const int xcd = b & 7, s = b >> 3;           // s: 0..79
  const int mt = xcd + 8*(s >> 3);             // 0..79 (stride-8 per XCD)
  const int nt = s & 7;                        // 0..7
  int e = te128[mt];
  if (e < 0) return;
  e &= 7;
  __shared__ alignas(16) unsigned short As[3][MT*KSTEP];   // 3 x 8 KB
  __shared__ alignas(16) unsigned short Bs[3][MT*KSTEP];
  const int tid = threadIdx.x;
  const int lane = tid & 63;
  const int wr = ((tid >> 7) & 1) * 64;
  const int wc = ((tid >> 6) & 1) * 64;
  unsigned short* const As0 = &As[0][0];
  unsigned short* const Bs0 = &Bs[0][0];
  const int BSZ = MT*KSTEP;

  long aoff[2]; long boff[2]; int dstIdx[2];
  #pragma unroll
  for (int i=0;i<2;i++){
    int idx = tid + 256*i;
    int r = idx >> 2, c = idx & 3;
    int sc = c ^ ((r >> 1) & 3);
    aoff[i] = (long)(mt*MT + r) * FF + sc*8;
    boff[i] = ((long)e*D_MODEL + nt*MT + r) * FF + sc*8;
    dstIdx[i] = idx * 8;
  }
  f32x4 zero = {0.f,0.f,0.f,0.f};
  f32x4 acc[4][4];
  #pragma unroll
  for (int i=0;i<4;i++)
    #pragma unroll
    for (int j=0;j<4;j++) acc[i][j] = zero;

  // prologue: slice 0 -> buf0, slice 1 -> buf1
  #pragma unroll
  for (int i=0;i<2;i++) gl2lds16(Hg  + aoff[i],          As0 + dstIdx[i]);
  #pragma unroll
  for (int i=0;i<2;i++) gl2lds16(w2t + boff[i],          Bs0 + dstIdx[i]);
  #pragma unroll
  for (int i=0;i<2;i++) gl2lds16(Hg  + aoff[i] + KSTEP,  As0 + BSZ + dstIdx[i]);
  #pragma unroll
  for (int i=0;i<2;i++) gl2lds16(w2t + boff[i] + KSTEP,  Bs0 + BSZ + dstIdx[i]);

  const int NK = FF / KSTEP;                   // 64
  int cur = 0;
  for (int t=0; t<NK; ++t){
    if (t+2 < NK){
      const int pf = (cur == 0) ? 2 : cur-1;
      const long k0 = (long)(t+2)*KSTEP;
      const int pdst = pf*BSZ;
      #pragma unroll
      for (int i=0;i<2;i++) gl2lds16(Hg  + aoff[i] + k0, As0 + pdst + dstIdx[i]);
      #pragma unroll
      for (int i=0;i<2;i++) gl2lds16(w2t + boff[i] + k0, Bs0 + pdst + dstIdx[i]);
      asm volatile("s_waitcnt vmcnt(8)" ::: "memory");
    } else if (t+1 < NK){
      asm volatile("s_waitcnt vmcnt(4)" ::: "memory");
    } else {
      asm volatile("s_waitcnt vmcnt(0)" ::: "memory");
    }
    __builtin_amdgcn_s_barrier();
    asm volatile("" ::: "memory");

    const unsigned short* Ac = As0 + cur*BSZ;
    const unsigned short* Bc = Bs0 + cur*BSZ;
    const int q = lane >> 4;
    bf16x8 a[4], bb[4];
    #pragma unroll
    for (int i=0;i<4;i++){
      int r = wr + i*16 + (lane & 15);
      a[i] = *reinterpret_cast<const bf16x8*>(&Ac[r*KSTEP + ((q ^ ((r>>1)&3))*8)]);
    }
    #pragma unroll
    for (int j=0;j<4;j++){
      int n = wc + j*16 + (lane & 15);
      bb[j] = *reinterpret_cast<const bf16x8*>(&Bc[n*KSTEP + ((q ^ ((n>>1)&3))*8)]);
    }
    #pragma unroll
    for (int i=0;i<4;i++)
      #pragma unroll
      for (int j=0;j<4;j++)
        acc[i][j] = __builtin_amdgcn_mfma_f32_16x16x32_bf16(a[i], bb[j], acc[i][j], 0,0,0);

    asm volatile("s_waitcnt lgkmcnt(0)" ::: "memory");
    __builtin_amdgcn_s_barrier();
    asm volatile("" ::: "memory");
    cur = (cur == 2) ? 0 : cur+1;
  }
  const int mrow0 = mt*MT + wr + ((lane >> 4) << 2);
  const int ncol0 = nt*MT + wc + (lane & 15);
  #pragma unroll
  for (int i=0;i<4;i++)
    #pragma unroll
    for (int j=0;j<4;j++)
      #pragma unroll
      for (int rr=0;rr<4;rr++)
        Yg[(long)(mrow0 + i*16 + rr)*D_MODEL + (ncol0 + j*16)] = acc[i][j][rr];
#undef KSTEP
}

// ---------------- combine: out[t] = w0*Yg[r0] + w1*Yg[r1]  (fp32) ------------
__global__ __launch_bounds__(256) void combine_kernel(
    const float* __restrict__ Yg, const float* __restrict__ topw,
    const int* __restrict__ rowOf, float* __restrict__ out)
{
  const int t = blockIdx.x;
  const int d = threadIdx.x * 4;
  const float wA = topw[2*t], wB = topw[2*t+1];
  long rA = rowOf[2*t], rB = rowOf[2*t+1];
  if (rA < 0 || rA >= MAXROWS) rA = 0;
  if (rB < 0 || rB >= MAXROWS) rB = 0;
  float4 a = *reinterpret_cast<const float4*>(Yg + rA*D_MODEL + d);
  float4 b = *reinterpret_cast<const float4*>(Yg + rB*D_MODEL + d);
  float4 o;
  o.x = wA*a.x + wB*b.x;
  o.y = wA*a.y + wB*b.y;
  o.z = wA*a.z + wB*b.z;
  o.w = wA*a.w + wB*b.w;
  *reinterpret_cast<float4*>(out + (long)t*D_MODEL + d) = o;
}

// ---------------- launch ----------------
extern "C" void kernel_launch(void* const* d_in, const int* in_sizes, int n_in,
                              void* d_out, int out_size, void* d_ws, size_t ws_size,
                              hipStream_t stream)
{
  const float* x  = (const float*)d_in[0];
  const float* w1 = (const float*)d_in[1];
  const float* v1 = (const float*)d_in[2];
  const float* w2 = (const float*)d_in[3];
  const float* rw = (const float*)d_in[4];
  float* out = (float*)d_out;
  (void)in_sizes; (void)n_in;

  // --- workspace layout + budget check ---
  size_t need = 0;
  auto count = [&](size_t b){ size_t r = need; need += (b + 255) & ~(size_t)255; return r; };
  size_t o_topw = count((size_t)NTOK*TOPK*sizeof(float));
  size_t o_tope = count((size_t)NTOK*TOPK*sizeof(int));
  size_t o_ctrl = count(64*sizeof(int));
  size_t o_seg  = count(16*sizeof(int));
  size_t o_te   = count(128*sizeof(int));                 // te256[40] + te128[80]
  size_t o_perm = count((size_t)MAXROWS*sizeof(int));
  size_t o_rowOf= count((size_t)NTOK*TOPK*sizeof(int));
  size_t o_xb   = count((size_t)NTOK*D_MODEL*2);          // bf16 x
  size_t o_w1b  = count((size_t)NEXP*FF*D_MODEL*2);       // bf16 w1
  size_t o_v1b  = count((size_t)NEXP*FF*D_MODEL*2);       // bf16 v1
  size_t o_w2t  = count((size_t)NEXP*D_MODEL*FF*2);       // bf16 w2^T
  size_t o_Hg   = count((size_t)MAXROWS*FF*2);            // bf16 hidden
  size_t o_Yg   = count((size_t)MAXROWS*D_MODEL*sizeof(float)); // fp32 expert out

  if (ws_size < need){
    zero_out_kernel<<<(out_size+255)/256, 256, 0, stream>>>(out, out_size);
    return;
  }

  char* base = (char*)d_ws;
  float* topw      = (float*)(base + o_topw);
  int*   tope      = (int*)  (base + o_tope);
  int*   ctrl      = (int*)  (base + o_ctrl);   // counts=ctrl[0..7], fill=ctrl[8..15]
  int*   segStart  = (int*)  (base + o_seg);
  int*   te256     = (int*)  (base + o_te);
  int*   te128     = te256 + 48;
  int*   perm      = (int*)  (base + o_perm);
  int*   rowOf     = (int*)  (base + o_rowOf);
  unsigned short* xb  = (unsigned short*)(base + o_xb);
  unsigned short* w1b = (unsigned short*)(base + o_w1b);
  unsigned short* v1b = (unsigned short*)(base + o_v1b);
  unsigned short* w2t = (unsigned short*)(base + o_w2t);
  unsigned short* Hg  = (unsigned short*)(base + o_Hg);
  float*          Yg  = (float*)         (base + o_Yg);

  const long nw4 = (long)NEXP*FF*D_MODEL/4;     // 4M float4s

  init_kernel     <<<(MAXROWS+255)/256, 256, 0, stream>>>(perm, ctrl);
  router_kernel   <<<NTOK/4, 256, 0, stream>>>(x, rw, topw, tope, ctrl, xb);
  partition_kernel<<<1, 64, 0, stream>>>(ctrl, segStart, te256, te128);
  scatter_kernel  <<<NTOK*TOPK/256, 256, 0, stream>>>(tope, segStart, ctrl+8, perm, rowOf);
  conv_kernel     <<<(nw4+255)/256, 256, 0, stream>>>(w1, w1b, nw4);
  conv_kernel     <<<(nw4+255)/256, 256, 0, stream>>>(v1, v1b, nw4);
  transpose_w2    <<<dim3(D_MODEL/32, FF/32, NEXP), dim3(32,8), 0, stream>>>(w2, w2t);
  gemm1_swiglu    <<<NT256*(FF/128), 512, 0, stream>>>(xb, w1b, v1b, perm, te256, Hg);
  gemm2_kernel    <<<NT128*(D_MODEL/MT), 256, 0, stream>>>(Hg, w2t, te128, Yg);
  combine_kernel  <<<NTOK, 256, 0, stream>>>(Yg, topw, rowOf, out);
}

// Round 5
// 555.372 us; speedup vs baseline: 1.4282x; 1.4282x over previous
//
#include <hip/hip_runtime.h>
#include <hip/hip_bf16.h>
#include <stdint.h>

// Problem constants (B=2, S=2048, D=1024, E=8, F=2048, K=2)
// Inputs/outputs are FLOAT32 (per reference). Internal compute: bf16 MFMA.
#define D_MODEL 1024
#define NEXP 8
#define FF 2048
#define TOPK 2
#define NTOK 4096                       // B*S tokens
#define MT2 256                         // gemm1 M-tile (rows)
#define MT 128                          // gemm2 M-tile (rows)
#define MAXROWS 10240                   // 8192 + 8*256 (worst-case padded rows)
#define NT256 40                        // 256-row tiles (gemm1)
#define NT128 80                        // 128-row tiles (gemm2)

typedef __bf16 bf16x8 __attribute__((ext_vector_type(8)));
typedef float f32x4 __attribute__((ext_vector_type(4)));

__device__ inline unsigned short f2b(float f){
  __hip_bfloat16 h = __float2bfloat16(f);
  return __builtin_bit_cast(unsigned short, h);
}

// async global->LDS, 16B per lane; LDS dst is wave-uniform base + lane*16
__device__ inline void gl2lds16(const unsigned short* g, unsigned short* l){
  __builtin_amdgcn_global_load_lds(
      (const __attribute__((address_space(1))) unsigned int*)g,
      (__attribute__((address_space(3))) unsigned int*)l, 16, 0, 0);
}

// ---------------- fallback: zero output (diagnostic path if ws too small) ----
__global__ void zero_out_kernel(float* out, int n){
  int i = blockIdx.x*256 + threadIdx.x;
  if (i < n) out[i] = 0.f;
}

// ---------------- fp32 -> bf16 conversion (vectorized) ----------------
__global__ __launch_bounds__(256) void conv_kernel(
    const float* __restrict__ in, unsigned short* __restrict__ out, long n4)
{
  long i = (long)blockIdx.x*256 + threadIdx.x;
  if (i >= n4) return;
  float4 v = reinterpret_cast<const float4*>(in)[i];
  ushort4 o;
  o.x = f2b(v.x); o.y = f2b(v.y); o.z = f2b(v.z); o.w = f2b(v.w);
  reinterpret_cast<ushort4*>(out)[i] = o;
}

// ---------------- bookkeeping kernels ----------------

__global__ void init_kernel(int* perm, int* ctrl){
  int i = blockIdx.x*256 + threadIdx.x;
  if (i < MAXROWS) perm[i] = -1;
  if (i < 64) ctrl[i] = 0;
}

// One wave per token: float4-vectorized logits + fused x->bf16 writeout.
__global__ __launch_bounds__(256) void router_kernel(
    const float* __restrict__ x, const float* __restrict__ rw,
    float* __restrict__ topw, int* __restrict__ tope, int* __restrict__ counts,
    unsigned short* __restrict__ xb)
{
  const int wid = threadIdx.x >> 6, lane = threadIdx.x & 63;
  const int t = blockIdx.x*4 + wid;
  float p[NEXP];
  #pragma unroll
  for (int e=0;e<NEXP;e++) p[e] = 0.f;
  #pragma unroll
  for (int j=0;j<4;j++){
    const int d4 = j*64 + lane;
    float4 xv = reinterpret_cast<const float4*>(x + (long)t*D_MODEL)[d4];
    ushort4 o; o.x=f2b(xv.x); o.y=f2b(xv.y); o.z=f2b(xv.z); o.w=f2b(xv.w);
    reinterpret_cast<ushort4*>(xb + (long)t*D_MODEL)[d4] = o;
    #pragma unroll
    for (int e=0;e<NEXP;e++){
      float4 rv = reinterpret_cast<const float4*>(rw + e*D_MODEL)[d4];
      p[e] += xv.x*rv.x + xv.y*rv.y + xv.z*rv.z + xv.w*rv.w;
    }
  }
  #pragma unroll
  for (int e=0;e<NEXP;e++)
    for (int off=32; off; off>>=1) p[e] += __shfl_xor(p[e], off, 64);
  if (lane == 0){
    float mx = p[0];
    #pragma unroll
    for (int e=1;e<NEXP;e++) mx = fmaxf(mx, p[e]);
    float w[NEXP]; float s = 0.f;
    #pragma unroll
    for (int e=0;e<NEXP;e++){ w[e] = expf(p[e]-mx); s += w[e]; }
    #pragma unroll
    for (int e=0;e<NEXP;e++) w[e] /= s;
    int e1 = 0;
    #pragma unroll
    for (int e=1;e<NEXP;e++) if (w[e] > w[e1]) e1 = e;   // ties -> lowest idx
    int e2 = -1;
    #pragma unroll
    for (int e=0;e<NEXP;e++) if (e != e1 && (e2 < 0 || w[e] > w[e2])) e2 = e;
    float s2 = w[e1] + w[e2];
    topw[t*2+0] = w[e1]/s2;
    topw[t*2+1] = w[e2]/s2;
    tope[t*2+0] = e1; tope[t*2+1] = e2;
    atomicAdd(&counts[e1], 1); atomicAdd(&counts[e2], 1);
  }
}

// pad each expert segment to 256 rows; emit tile->expert for 256- and 128-tiles
__global__ void partition_kernel(const int* ctrl, int* segStart,
                                 int* te256, int* te128){
  if (threadIdx.x == 0 && blockIdx.x == 0){
    int off = 0, t2 = 0, t1 = 0;
    for (int e=0;e<NEXP;e++){
      segStart[e] = off;
      int padded = ((ctrl[e] + MT2 - 1)/MT2)*MT2;
      off += padded;
      for (int k=0;k<padded/MT2 && t2 < NT256;k++) te256[t2++] = e;
      for (int k=0;k<padded/MT  && t1 < NT128;k++) te128[t1++] = e;
    }
    segStart[NEXP] = off;
    while (t2 < NT256) te256[t2++] = -1;
    while (t1 < NT128) te128[t1++] = -1;
  }
}

__global__ void scatter_kernel(const int* tope, const int* segStart, int* fill,
                               int* perm, int* rowOf){
  int i = blockIdx.x*256 + threadIdx.x;           // (token,k) pair index
  int e = tope[i];
  int pos = segStart[e] + atomicAdd(&fill[e], 1);
  if (pos >= 0 && pos < MAXROWS){ perm[pos] = i >> 1; rowOf[i] = pos; }
}

// w2 (E,F,D) fp32 -> w2t (E,D,F) bf16: transpose + convert fused
__global__ void transpose_w2(const float* __restrict__ w2,
                             unsigned short* __restrict__ w2t){
  __shared__ unsigned short tl[32][33];
  const int e = blockIdx.z;
  const int d0 = blockIdx.x*32, f0 = blockIdx.y*32;
  const int tx = threadIdx.x, ty = threadIdx.y;
  #pragma unroll
  for (int i=0;i<4;i++)
    tl[ty + i*8][tx] = f2b(w2[((long)(e*FF + f0 + ty + i*8))*D_MODEL + d0 + tx]);
  __syncthreads();
  #pragma unroll
  for (int i=0;i<4;i++)
    w2t[((long)e*D_MODEL + d0 + ty + i*8)*FF + f0 + tx] = tl[tx][ty + i*8];
}

// ---------------- GEMM1: Hg = silu(Xg @ w1e^T) * (Xg @ v1e^T) ----------------
// SINGLE-ACCUMULATOR SwiGLU GEMM via interleaved B (round-5 restructure):
//   The round-3/4 dual accumulator (acc1+acc2 = 128 regs) blew the unified
//   VGPR+AGPR budget (256 total at 2 waves/EU) -> ~30 reg spill -> 540 MB
//   scratch writebacks. Fix: ONE GEMM whose B-tile interleaves w1/v1 in
//   16-col groups: LDS B row n, group g=n>>4: g even -> w1, g odd -> v1,
//   both at unit f = nt*64 + (g>>1)*16 + (n&15). Within a wave, frag j=0
//   is the g-mat and j=1 the u-mat for the SAME f and SAME lane, so the
//   epilogue is thread-local: h = silu(acc[m][0][rr]) * acc[m][1][rr].
//   acc[8][2] = 64 VGPR; total demand ~120 -> no spill under any cap.
// Geometry: BM=256 BN=128(=64 f/block), 512 thr, waves 2Mx4N, per-wave
//   128x32. 4 phases/K-tile (kk x M-half), 8 MFMA/phase. LDS 96 KB
//   (A 2buf x 2kk x 16KB, B 2buf x 2kk x 8KB) -> 1 block/CU.
// Counted-vmcnt ledger (per-thread loads/K-tile = 6: A 2+2, B 1+1), issue
//   order A0,B0,A1,B1 one panel/phase into buf^1:
//   steady waits ph0..3 = vmcnt(5),(6),(5),(6); final tile (3),(3),(0),(0).
// Swizzle: chunk c' = c ^ ((row>>1)&3) on both the pre-swizzled global
// source and the ds_read side (2-way bank aliasing = free).
__global__ __launch_bounds__(512) void gemm1_swiglu(
    const unsigned short* __restrict__ x,
    const unsigned short* __restrict__ w1,
    const unsigned short* __restrict__ v1,
    const int* __restrict__ perm,
    const int* __restrict__ te256,
    unsigned short* __restrict__ Hg)
{
  const int b = blockIdx.x;                    // 0..1279
  const int xcd = b & 7, s = b >> 3;           // s: 0..159
  const int mt = xcd*5 + (s % 5);              // 0..39 (5-mt stripe per XCD)
  const int nt = s / 5;                        // 0..31 (64 f-units each)
  int e = te256[mt];
  if (e < 0) return;
  e &= 7;
  __shared__ alignas(16) unsigned short As[2][2][8192];   // [buf][kk][256*32]
  __shared__ alignas(16) unsigned short Bs[2][2][4096];   // [buf][kk][128*32] interleaved
  const int tid = threadIdx.x;
  const int lane = tid & 63;
  const int wid = tid >> 6;
  const int wm = wid >> 2, wn = wid & 3;       // 2M x 4N waves

  // A staging: 2 chunks/thread. chunk idx -> row = idx>>2, c = idx&3
  const int ra = tid >> 2, ca = tid & 3;
  const int sca = ca ^ ((ra >> 1) & 3);        // same for ra and ra+128
  int tok0 = perm[mt*MT2 + ra];        if (tok0 < 0 || tok0 >= NTOK) tok0 = 0;
  int tok1 = perm[mt*MT2 + ra + 128];  if (tok1 < 0 || tok1 >= NTOK) tok1 = 0;
  const long aS0 = (long)tok0*D_MODEL + sca*8;
  const long aS1 = (long)tok1*D_MODEL + sca*8;
  const int dA0 = tid*8, dA1 = (tid+512)*8;

  // B staging: 1 chunk/thread, interleaved w1/v1 source (row = ra, c = ca)
  const int gB = ra >> 4, ccB = ra & 15;       // group, within-group col
  const unsigned short* bsrc = (gB & 1) ? v1 : w1;
  const long bS = ((long)e*FF + nt*64 + (gB>>1)*16 + ccB)*D_MODEL + sca*8;
  const int dB = tid*8;

  f32x4 zero = {0.f,0.f,0.f,0.f};
  f32x4 acc[8][2];
  #pragma unroll
  for (int i=0;i<8;i++){ acc[i][0] = zero; acc[i][1] = zero; }

  // ds_read addressing (row stride = 32 elems within a [kk] panel)
  const int lq = lane >> 4, ll = lane & 15;
  const int scol = (lq ^ ((ll >> 1) & 3)) * 8;        // swizzled chunk offset
  const int aRow = (wm*128 + ll)*32 + scol;           // + (h*64 + i*16)*32
  const int nRow = (wn*32  + ll)*32 + scol;           // + j*16*32

#define VMW(n) asm volatile("s_waitcnt vmcnt(" #n ")" ::: "memory")
#define BAR()  do{ asm volatile("" ::: "memory"); __builtin_amdgcn_s_barrier(); \
                   asm volatile("" ::: "memory"); }while(0)
#define STAGE_A(BUF,KK,KT) do{ const long o_ = (long)(KT)*64 + (KK)*32; \
    gl2lds16(x + aS0 + o_, &As[BUF][KK][0] + dA0);                      \
    gl2lds16(x + aS1 + o_, &As[BUF][KK][0] + dA1); }while(0)
#define STAGE_B(BUF,KK,KT) do{ const long o_ = (long)(KT)*64 + (KK)*32; \
    gl2lds16(bsrc + bS + o_, &Bs[BUF][KK][0] + dB); }while(0)
// phase compute: M-half H_ (0/1); LOADB_: refresh b frags (once per kk)
#define PHASE(BUF_,KK_,H_,LOADB_) do{                                   \
    const unsigned short* Ap = &As[BUF_][KK_][0];                       \
    if (LOADB_){                                                        \
      const unsigned short* Bp = &Bs[BUF_][KK_][0];                     \
      bf[0] = *(const bf16x8*)&Bp[nRow];                                \
      bf[1] = *(const bf16x8*)&Bp[nRow + 512];                          \
    }                                                                   \
    bf16x8 af[4];                                                       \
    _Pragma("unroll")                                                   \
    for (int i=0;i<4;i++) af[i] = *(const bf16x8*)&Ap[aRow + ((H_)*64 + i*16)*32]; \
    __builtin_amdgcn_s_setprio(1);                                      \
    _Pragma("unroll")                                                   \
    for (int i=0;i<4;i++){                                              \
      acc[(H_)*4+i][0] = __builtin_amdgcn_mfma_f32_16x16x32_bf16(af[i], bf[0], acc[(H_)*4+i][0], 0,0,0); \
      acc[(H_)*4+i][1] = __builtin_amdgcn_mfma_f32_16x16x32_bf16(af[i], bf[1], acc[(H_)*4+i][1], 0,0,0); \
    }                                                                   \
    __builtin_amdgcn_s_setprio(0);                                      \
  }while(0)

  // prologue: stage K-tile 0 fully (A0,B0,A1,B1 = 6 loads/thread)
  STAGE_A(0,0,0); STAGE_B(0,0,0); STAGE_A(0,1,0); STAGE_B(0,1,0);

  bf16x8 bf[2];
  const int NKT = D_MODEL/64;                  // 16
  for (int kt=0; kt<NKT; ++kt){
    const int buf = kt & 1, nb = buf ^ 1;
    const bool pre = (kt+1 < NKT);
    // ph0: kk0 half0 (loads B frags kk0)
    if (pre){ STAGE_A(nb,0,kt+1); VMW(5); } else { VMW(3); }
    BAR();
    if (buf == 0) PHASE(0,0,0,1); else PHASE(1,0,0,1);
    // ph1: kk0 half1
    if (pre){ STAGE_B(nb,0,kt+1); VMW(6); } else { VMW(3); }
    BAR();
    if (buf == 0) PHASE(0,0,1,0); else PHASE(1,0,1,0);
    // ph2: kk1 half0 (loads B frags kk1)
    if (pre){ STAGE_A(nb,1,kt+1); VMW(5); } else { VMW(0); }
    BAR();
    if (buf == 0) PHASE(0,1,0,1); else PHASE(1,1,0,1);
    // ph3: kk1 half1
    if (pre){ STAGE_B(nb,1,kt+1); VMW(6); } else { VMW(0); }
    BAR();
    if (buf == 0) PHASE(0,1,1,0); else PHASE(1,1,1,0);
  }
#undef PHASE
#undef STAGE_A
#undef STAGE_B
#undef VMW
#undef BAR

  // epilogue: h = silu(g)*u thread-local (frag j=0 = g, j=1 = u, same f).
  // C/D: col=lane&15, row=(lane>>4)*4+rr
  const int mrowB = mt*MT2 + wm*128 + lq*4;
  const int fcol  = nt*64 + wn*16 + ll;
  #pragma unroll
  for (int m=0;m<8;m++)
    #pragma unroll
    for (int rr=0;rr<4;rr++){
      float g = acc[m][0][rr];
      float u = acc[m][1][rr];
      float h = (g / (1.0f + __expf(-g))) * u;
      Hg[(long)(mrowB + m*16 + rr)*FF + fcol] = f2b(h);
    }
}

// ---------------- GEMM2: Yg(fp32) = Hg @ w2e  (B from transposed w2t) --------
// 3-buffer depth-2 ring (verified round 2); 48 KB LDS -> 3 blocks/CU.
__global__ __launch_bounds__(256, 3) void gemm2_kernel(
    const unsigned short* __restrict__ Hg,
    const unsigned short* __restrict__ w2t,   // [E][D][F] bf16
    const int* __restrict__ te128,
    float* __restrict__ Yg)
{
#define KSTEP 32
  const int b = blockIdx.x;                    // 0..639
  const int xcd = b & 7, s = b >> 3;           // s: 0..79
  const int mt = xcd + 8*(s >> 3);             // 0..79 (stride-8 per XCD)
  const int nt = s & 7;                        // 0..7
  int e = te128[mt];
  if (e < 0) return;
  e &= 7;
  __shared__ alignas(16) unsigned short As[3][MT*KSTEP];   // 3 x 8 KB
  __shared__ alignas(16) unsigned short Bs[3][MT*KSTEP];
  const int tid = threadIdx.x;
  const int lane = tid & 63;
  const int wr = ((tid >> 7) & 1) * 64;
  const int wc = ((tid >> 6) & 1) * 64;
  unsigned short* const As0 = &As[0][0];
  unsigned short* const Bs0 = &Bs[0][0];
  const int BSZ = MT*KSTEP;

  long aoff[2]; long boff[2]; int dstIdx[2];
  #pragma unroll
  for (int i=0;i<2;i++){
    int idx = tid + 256*i;
    int r = idx >> 2, c = idx & 3;
    int sc = c ^ ((r >> 1) & 3);
    aoff[i] = (long)(mt*MT + r) * FF + sc*8;
    boff[i] = ((long)e*D_MODEL + nt*MT + r) * FF + sc*8;
    dstIdx[i] = idx * 8;
  }
  f32x4 zero = {0.f,0.f,0.f,0.f};
  f32x4 acc[4][4];
  #pragma unroll
  for (int i=0;i<4;i++)
    #pragma unroll
    for (int j=0;j<4;j++) acc[i][j] = zero;

  // prologue: slice 0 -> buf0, slice 1 -> buf1
  #pragma unroll
  for (int i=0;i<2;i++) gl2lds16(Hg  + aoff[i],          As0 + dstIdx[i]);
  #pragma unroll
  for (int i=0;i<2;i++) gl2lds16(w2t + boff[i],          Bs0 + dstIdx[i]);
  #pragma unroll
  for (int i=0;i<2;i++) gl2lds16(Hg  + aoff[i] + KSTEP,  As0 + BSZ + dstIdx[i]);
  #pragma unroll
  for (int i=0;i<2;i++) gl2lds16(w2t + boff[i] + KSTEP,  Bs0 + BSZ + dstIdx[i]);

  const int NK = FF / KSTEP;                   // 64
  int cur = 0;
  for (int t=0; t<NK; ++t){
    if (t+2 < NK){
      const int pf = (cur == 0) ? 2 : cur-1;
      const long k0 = (long)(t+2)*KSTEP;
      const int pdst = pf*BSZ;
      #pragma unroll
      for (int i=0;i<2;i++) gl2lds16(Hg  + aoff[i] + k0, As0 + pdst + dstIdx[i]);
      #pragma unroll
      for (int i=0;i<2;i++) gl2lds16(w2t + boff[i] + k0, Bs0 + pdst + dstIdx[i]);
      asm volatile("s_waitcnt vmcnt(8)" ::: "memory");
    } else if (t+1 < NK){
      asm volatile("s_waitcnt vmcnt(4)" ::: "memory");
    } else {
      asm volatile("s_waitcnt vmcnt(0)" ::: "memory");
    }
    __builtin_amdgcn_s_barrier();
    asm volatile("" ::: "memory");

    const unsigned short* Ac = As0 + cur*BSZ;
    const unsigned short* Bc = Bs0 + cur*BSZ;
    const int q = lane >> 4;
    bf16x8 a[4], bb[4];
    #pragma unroll
    for (int i=0;i<4;i++){
      int r = wr + i*16 + (lane & 15);
      a[i] = *reinterpret_cast<const bf16x8*>(&Ac[r*KSTEP + ((q ^ ((r>>1)&3))*8)]);
    }
    #pragma unroll
    for (int j=0;j<4;j++){
      int n = wc + j*16 + (lane & 15);
      bb[j] = *reinterpret_cast<const bf16x8*>(&Bc[n*KSTEP + ((q ^ ((n>>1)&3))*8)]);
    }
    #pragma unroll
    for (int i=0;i<4;i++)
      #pragma unroll
      for (int j=0;j<4;j++)
        acc[i][j] = __builtin_amdgcn_mfma_f32_16x16x32_bf16(a[i], bb[j], acc[i][j], 0,0,0);

    asm volatile("s_waitcnt lgkmcnt(0)" ::: "memory");
    __builtin_amdgcn_s_barrier();
    asm volatile("" ::: "memory");
    cur = (cur == 2) ? 0 : cur+1;
  }
  const int mrow0 = mt*MT + wr + ((lane >> 4) << 2);
  const int ncol0 = nt*MT + wc + (lane & 15);
  #pragma unroll
  for (int i=0;i<4;i++)
    #pragma unroll
    for (int j=0;j<4;j++)
      #pragma unroll
      for (int rr=0;rr<4;rr++)
        Yg[(long)(mrow0 + i*16 + rr)*D_MODEL + (ncol0 + j*16)] = acc[i][j][rr];
#undef KSTEP
}

// ---------------- combine: out[t] = w0*Yg[r0] + w1*Yg[r1]  (fp32) ------------
__global__ __launch_bounds__(256) void combine_kernel(
    const float* __restrict__ Yg, const float* __restrict__ topw,
    const int* __restrict__ rowOf, float* __restrict__ out)
{
  const int t = blockIdx.x;
  const int d = threadIdx.x * 4;
  const float wA = topw[2*t], wB = topw[2*t+1];
  long rA = rowOf[2*t], rB = rowOf[2*t+1];
  if (rA < 0 || rA >= MAXROWS) rA = 0;
  if (rB < 0 || rB >= MAXROWS) rB = 0;
  float4 a = *reinterpret_cast<const float4*>(Yg + rA*D_MODEL + d);
  float4 b = *reinterpret_cast<const float4*>(Yg + rB*D_MODEL + d);
  float4 o;
  o.x = wA*a.x + wB*b.x;
  o.y = wA*a.y + wB*b.y;
  o.z = wA*a.z + wB*b.z;
  o.w = wA*a.w + wB*b.w;
  *reinterpret_cast<float4*>(out + (long)t*D_MODEL + d) = o;
}

// ---------------- launch ----------------
extern "C" void kernel_launch(void* const* d_in, const int* in_sizes, int n_in,
                              void* d_out, int out_size, void* d_ws, size_t ws_size,
                              hipStream_t stream)
{
  const float* x  = (const float*)d_in[0];
  const float* w1 = (const float*)d_in[1];
  const float* v1 = (const float*)d_in[2];
  const float* w2 = (const float*)d_in[3];
  const float* rw = (const float*)d_in[4];
  float* out = (float*)d_out;
  (void)in_sizes; (void)n_in;

  // --- workspace layout + budget check ---
  size_t need = 0;
  auto count = [&](size_t b){ size_t r = need; need += (b + 255) & ~(size_t)255; return r; };
  size_t o_topw = count((size_t)NTOK*TOPK*sizeof(float));
  size_t o_tope = count((size_t)NTOK*TOPK*sizeof(int));
  size_t o_ctrl = count(64*sizeof(int));
  size_t o_seg  = count(16*sizeof(int));
  size_t o_te   = count(128*sizeof(int));                 // te256[40] + te128[80]
  size_t o_perm = count((size_t)MAXROWS*sizeof(int));
  size_t o_rowOf= count((size_t)NTOK*TOPK*sizeof(int));
  size_t o_xb   = count((size_t)NTOK*D_MODEL*2);          // bf16 x
  size_t o_w1b  = count((size_t)NEXP*FF*D_MODEL*2);       // bf16 w1
  size_t o_v1b  = count((size_t)NEXP*FF*D_MODEL*2);       // bf16 v1
  size_t o_w2t  = count((size_t)NEXP*D_MODEL*FF*2);       // bf16 w2^T
  size_t o_Hg   = count((size_t)MAXROWS*FF*2);            // bf16 hidden
  size_t o_Yg   = count((size_t)MAXROWS*D_MODEL*sizeof(float)); // fp32 expert out

  if (ws_size < need){
    zero_out_kernel<<<(out_size+255)/256, 256, 0, stream>>>(out, out_size);
    return;
  }

  char* base = (char*)d_ws;
  float* topw      = (float*)(base + o_topw);
  int*   tope      = (int*)  (base + o_tope);
  int*   ctrl      = (int*)  (base + o_ctrl);   // counts=ctrl[0..7], fill=ctrl[8..15]
  int*   segStart  = (int*)  (base + o_seg);
  int*   te256     = (int*)  (base + o_te);
  int*   te128     = te256 + 48;
  int*   perm      = (int*)  (base + o_perm);
  int*   rowOf     = (int*)  (base + o_rowOf);
  unsigned short* xb  = (unsigned short*)(base + o_xb);
  unsigned short* w1b = (unsigned short*)(base + o_w1b);
  unsigned short* v1b = (unsigned short*)(base + o_v1b);
  unsigned short* w2t = (unsigned short*)(base + o_w2t);
  unsigned short* Hg  = (unsigned short*)(base + o_Hg);
  float*          Yg  = (float*)         (base + o_Yg);

  const long nw4 = (long)NEXP*FF*D_MODEL/4;     // 4M float4s

  init_kernel     <<<(MAXROWS+255)/256, 256, 0, stream>>>(perm, ctrl);
  router_kernel   <<<NTOK/4, 256, 0, stream>>>(x, rw, topw, tope, ctrl, xb);
  partition_kernel<<<1, 64, 0, stream>>>(ctrl, segStart, te256, te128);
  scatter_kernel  <<<NTOK*TOPK/256, 256, 0, stream>>>(tope, segStart, ctrl+8, perm, rowOf);
  conv_kernel     <<<(nw4+255)/256, 256, 0, stream>>>(w1, w1b, nw4);
  conv_kernel     <<<(nw4+255)/256, 256, 0, stream>>>(v1, v1b, nw4);
  transpose_w2    <<<dim3(D_MODEL/32, FF/32, NEXP), dim3(32,8), 0, stream>>>(w2, w2t);
  gemm1_swiglu    <<<NT256*(FF/64), 512, 0, stream>>>(xb, w1b, v1b, perm, te256, Hg);
  gemm2_kernel    <<<NT128*(D_MODEL/MT), 256, 0, stream>>>(Hg, w2t, te128, Yg);
  combine_kernel  <<<NTOK, 256, 0, stream>>>(Yg, topw, rowOf, out);
}